// Round 5
// baseline (264.901 us; speedup 1.0000x reference)
//
#include <hip/hip_runtime.h>

#define TTHR 0.001f
#define QSCALE 0.17677669529663687f   // 1/sqrt(32)
#define CAP 16
#define YSCALE 8388608.0f             // 2^23
#define YINV   1.1920928955078125e-07f // 2^-23

typedef _Float16 half4v __attribute__((ext_vector_type(4)));
typedef _Float16 half8v __attribute__((ext_vector_type(8)));
typedef float f32x4 __attribute__((ext_vector_type(4)));

// XCD-aware block swizzle: contiguous logical range per XCD (grid % 8 == 0).
__device__ __forceinline__ int xcd_bid() {
  return (blockIdx.x & 7) * ((int)gridDim.x >> 3) + ((int)blockIdx.x >> 3);
}

// ---- stage a 128x64-half tile into LDS, XOR-swizzled, arbitrary row stride ----
// LDS granule (row, x) holds source granule (row, x ^ (row&7)); 16B granules.
// global_load_lds writes linearly (wave base + lane*16) -> inverse perm on source.
__device__ __forceinline__ void stage_tile_s(const _Float16* __restrict__ gsrc,
                                             int rowstride, _Float16* lds, int tid)
{
  const int lane = tid & 63;
  const int w4 = (tid >> 6) << 2;
#pragma unroll
  for (int r = 0; r < 4; ++r) {
    const int p = (w4 + r) * 64 + lane;
    const int row = p >> 3, xg = p & 7;
    __builtin_amdgcn_global_load_lds(
        (const __attribute__((address_space(1))) void*)(gsrc + row * rowstride + ((xg ^ (row & 7)) << 3)),
        (__attribute__((address_space(3))) void*)(lds + (w4 + r) * 512),
        16, 0, 0);
  }
}

// ---- stage a 64x64-half tile (512 granules) ----
__device__ __forceinline__ void stage_tile64(const _Float16* __restrict__ gsrc,
                                             int rowstride, _Float16* lds, int tid)
{
  const int lane = tid & 63;
  const int w2 = (tid >> 6) << 1;
#pragma unroll
  for (int r = 0; r < 2; ++r) {
    const int p = (w2 + r) * 64 + lane;
    const int row = p >> 3, xg = p & 7;
    __builtin_amdgcn_global_load_lds(
        (const __attribute__((address_space(1))) void*)(gsrc + row * rowstride + ((xg ^ (row & 7)) << 3)),
        (__attribute__((address_space(3))) void*)(lds + (w2 + r) * 512),
        16, 0, 0);
  }
}

// ---------------- conversion kernels ----------------
__global__ __launch_bounds__(256) void k_split_rm(
    const float* __restrict__ in, _Float16* __restrict__ oh,
    _Float16* __restrict__ ol, int n4)
{
  const int i = blockIdx.x * 256 + threadIdx.x;
  if (i >= n4) return;
  float4 v = ((const float4*)in)[i];
  half4v h = {(_Float16)v.x, (_Float16)v.y, (_Float16)v.z, (_Float16)v.w};
  half4v l = {(_Float16)(v.x - (float)h[0]), (_Float16)(v.y - (float)h[1]),
              (_Float16)(v.z - (float)h[2]), (_Float16)(v.w - (float)h[3])};
  ((half4v*)oh)[i] = h;
  ((half4v*)ol)[i] = l;
}

__global__ __launch_bounds__(256) void k_split_tr(
    const float* __restrict__ in, _Float16* __restrict__ oh,
    _Float16* __restrict__ ol, int K, int N)
{
  __shared__ float t[32][33];
  const int nb = N >> 5;
  const int n0 = (blockIdx.x % nb) << 5, k0 = (blockIdx.x / nb) << 5;
  const int r = threadIdx.x >> 3, c4 = (threadIdx.x & 7) << 2;
  float4 v = *(const float4*)&in[(k0 + r) * N + n0 + c4];
  t[r][c4] = v.x; t[r][c4 + 1] = v.y; t[r][c4 + 2] = v.z; t[r][c4 + 3] = v.w;
  __syncthreads();
  float a0 = t[c4][r], a1 = t[c4 + 1][r], a2 = t[c4 + 2][r], a3 = t[c4 + 3][r];
  half4v h = {(_Float16)a0, (_Float16)a1, (_Float16)a2, (_Float16)a3};
  half4v l = {(_Float16)(a0 - (float)h[0]), (_Float16)(a1 - (float)h[1]),
              (_Float16)(a2 - (float)h[2]), (_Float16)(a3 - (float)h[3])};
  *(half4v*)&oh[(n0 + r) * K + k0 + c4] = h;
  *(half4v*)&ol[(n0 + r) * K + k0 + c4] = l;
}

// ---------------- split-fp16 MFMA GEMM, 128x64 tile, 2-phase dbuf ----------
// C = A(fp32 via Ah+Al) @ B^T(fp32 via Bh+Bl); A:[M][K], B stored [N][K].
// 3 passes: Ah*Bh + Ah*Bl + Al*Bh. 4 waves 2x2 -> wave tile 64x32.
template<int EPI>
__global__ __launch_bounds__(256) void k_gemm_split(
    const _Float16* __restrict__ Ah, const _Float16* __restrict__ Al,
    const _Float16* __restrict__ Bh, const _Float16* __restrict__ Bl,
    const float* __restrict__ bias, int K, int kclog, int nbn,
    float* __restrict__ out, _Float16* __restrict__ Qs,
    _Float16* __restrict__ Ks, float* __restrict__ Vp)
{
  __shared__ __align__(16) _Float16 Asm[2][8192];
  __shared__ __align__(16) _Float16 Bsm[2][4096];
  const int tid = threadIdx.x, lane = tid & 63, w = tid >> 6;
  const int wr = w >> 1, wc = w & 1;
  const int lrow = lane & 15, lk = lane >> 4;
  const int bid = xcd_bid();
  const int mt = bid / nbn, ct = bid % nbn;
  const int m0 = mt << 7, c0 = ct << 6;

  const int nch = 3 << kclog;
  const int kcm = (1 << kclog) - 1;
  stage_tile_s(Ah + (size_t)m0 * K, K, Asm[0], tid);
  stage_tile64(Bh + (size_t)c0 * K, K, Bsm[0], tid);
  __syncthreads();

  f32x4 acc[4][2] = {};
#pragma unroll 1
  for (int ch = 0; ch < nch; ++ch) {
    const int cur = ch & 1;
    if (ch + 1 < nch) {
      const int ch2 = ch + 1;
      const int phase = ch2 >> kclog, kc = ch2 & kcm;
      const _Float16* As = (phase == 2) ? Al : Ah;
      const _Float16* Bs = (phase == 1) ? Bl : Bh;
      stage_tile_s(As + (size_t)m0 * K + (kc << 6), K, Asm[cur ^ 1], tid);
      stage_tile64(Bs + (size_t)c0 * K + (kc << 6), K, Bsm[cur ^ 1], tid);
    }
#pragma unroll
    for (int ks = 0; ks < 2; ++ks) {
      half8v af[4], bf[2];
#pragma unroll
      for (int mi = 0; mi < 4; ++mi) {
        const int row = (wr << 6) + (mi << 4) + lrow;
        const int xg = ((ks << 2) + lk) ^ (row & 7);
        af[mi] = *(const half8v*)&Asm[cur][((row << 3) + xg) << 3];
      }
#pragma unroll
      for (int ni = 0; ni < 2; ++ni) {
        const int col = (wc << 5) + (ni << 4) + lrow;
        const int xg = ((ks << 2) + lk) ^ (col & 7);
        bf[ni] = *(const half8v*)&Bsm[cur][((col << 3) + xg) << 3];
      }
#pragma unroll
      for (int mi = 0; mi < 4; ++mi)
#pragma unroll
        for (int ni = 0; ni < 2; ++ni)
          acc[mi][ni] = __builtin_amdgcn_mfma_f32_16x16x32_f16(af[mi], bf[ni], acc[mi][ni], 0, 0, 0);
    }
    __syncthreads();
  }

#pragma unroll
  for (int ni = 0; ni < 2; ++ni) {
    const int c = c0 + (wc << 5) + (ni << 4) + lrow;
    const float bv = bias[c];
    if (EPI == 0) {
#pragma unroll
      for (int mi = 0; mi < 4; ++mi)
#pragma unroll
        for (int reg = 0; reg < 4; ++reg) {
          const int m = m0 + (wr << 6) + (mi << 4) + (lk << 2) + reg;
          out[m * 1024 + c] = acc[mi][ni][reg] * YINV + bv;
        }
    } else {
      const int part = c >> 8, cc = c & 255;
      const int h = cc >> 5, d = cc & 31;
#pragma unroll
      for (int mi = 0; mi < 4; ++mi)
#pragma unroll
        for (int reg = 0; reg < 4; ++reg) {
          const int m = m0 + (wr << 6) + (mi << 4) + (lk << 2) + reg;
          const int b = m >> 12, n = (m >> 2) & 1023, l = m & 3;
          const int panel = b * 32 + l * 8 + h;
          float v = acc[mi][ni][reg] + bv;
          if (part == 2) {
            Vp[(panel << 15) + n * 32 + d] = v;
          } else {
            _Float16* dst = part ? Ks : Qs;
            if (!part) v *= QSCALE;
            _Float16 hv = (_Float16)v;
            _Float16 lv = (_Float16)(v - (float)hv);
            dst[(panel << 16) + n * 64 + d] = hv;
            dst[(panel << 16) + n * 64 + 32 + d] = lv;
          }
        }
    }
  }
}

// ---------------- K2: scores -> exp -> row sums Z (per-row blocks) ----------
__global__ __launch_bounds__(256) void k_score_sum(
    const _Float16* __restrict__ Qs, const _Float16* __restrict__ Ks,
    float* __restrict__ Z)
{
  __shared__ __align__(16) _Float16 Qsm[8192];
  __shared__ __align__(16) _Float16 Ksm[2][8192];
  __shared__ float Zsh[128];
  const int tid = threadIdx.x, lane = tid & 63, w = tid >> 6;
  const int wr = w >> 1, wc = w & 1;
  const int lrow = lane & 15, lk = lane >> 4;
  const int bid = xcd_bid();
  const int rt = bid & 7, panel = bid >> 3;

  stage_tile_s(Qs + (panel << 16) + (rt << 13), 64, Qsm, tid);
  stage_tile_s(Ks + (panel << 16), 64, Ksm[0], tid);
  if (tid < 128) Zsh[tid] = 0.0f;
  __syncthreads();

  const int kstA[3] = {0, 0, 4}, kstB[3] = {0, 4, 0};
  half8v af[3][4];
#pragma unroll
  for (int ks = 0; ks < 3; ++ks)
#pragma unroll
    for (int mi = 0; mi < 4; ++mi) {
      const int row = (wr << 6) + (mi << 4) + lrow;
      const int xg = (kstA[ks] + lk) ^ (row & 7);
      af[ks][mi] = *(const half8v*)&Qsm[((row << 3) + xg) << 3];
    }

  float rsum[4][4] = {};
#pragma unroll 1
  for (int ct = 0; ct < 8; ++ct) {
    const int cur = ct & 1;
    if (ct < 7)
      stage_tile_s(Ks + (panel << 16) + ((ct + 1) << 13), 64, Ksm[cur ^ 1], tid);
    f32x4 acc[4][4] = {};
#pragma unroll
    for (int ks = 0; ks < 3; ++ks) {
      half8v bf[4];
#pragma unroll
      for (int ni = 0; ni < 4; ++ni) {
        const int col = (wc << 6) + (ni << 4) + lrow;
        const int xg = (kstB[ks] + lk) ^ (col & 7);
        bf[ni] = *(const half8v*)&Ksm[cur][((col << 3) + xg) << 3];
      }
#pragma unroll
      for (int mi = 0; mi < 4; ++mi)
#pragma unroll
        for (int ni = 0; ni < 4; ++ni)
          acc[mi][ni] = __builtin_amdgcn_mfma_f32_16x16x32_f16(af[ks][mi], bf[ni], acc[mi][ni], 0, 0, 0);
    }
#pragma unroll
    for (int mi = 0; mi < 4; ++mi)
#pragma unroll
      for (int reg = 0; reg < 4; ++reg)
#pragma unroll
        for (int ni = 0; ni < 4; ++ni)
          rsum[mi][reg] += __expf(acc[mi][ni][reg]);
    __syncthreads();
  }

#pragma unroll
  for (int mi = 0; mi < 4; ++mi)
#pragma unroll
    for (int reg = 0; reg < 4; ++reg) {
      float s = rsum[mi][reg];
      s += __shfl_xor(s, 1, 64);
      s += __shfl_xor(s, 2, 64);
      s += __shfl_xor(s, 4, 64);
      s += __shfl_xor(s, 8, 64);
      if (lrow == 0) atomicAdd(&Zsh[(wr << 6) + (mi << 4) + (lk << 2) + reg], s);
    }
  __syncthreads();
  if (tid < 128) Z[panel * 1024 + (rt << 7) + tid] = Zsh[tid];
}

// ---------------- K3: scores x4 levels -> product -> sparse emit ------------
// Single LDS buffer; per level: MFMA -> barrier -> issue stage(l+1) ->
// exp/prod(l) (hides stage latency) -> barrier.
// prod_l relu(exp(s)/Z - T) == (prod_l max(exp(s) - T*Z_l, 0)) / prod_l Z_l
__global__ __launch_bounds__(256) void k_comb2(
    const _Float16* __restrict__ Qs, const _Float16* __restrict__ Ks,
    const float* __restrict__ Z, int* __restrict__ ccnt,
    unsigned short* __restrict__ cidx, float* __restrict__ cval)
{
  __shared__ __align__(16) _Float16 Asm[8192];
  __shared__ __align__(16) _Float16 Bsm[8192];
  __shared__ float tzl[2][128];
  __shared__ float rzl[128];
  __shared__ int lcnt[128];
  const int tid = threadIdx.x, lane = tid & 63, w = tid >> 6;
  const int wr = w >> 1, wc = w & 1;
  const int lrow = lane & 15, lk = lane >> 4;
  const int bid = xcd_bid();
  const int ct = bid & 7, rt = (bid >> 3) & 7, bh = bid >> 6;
  const int b = bh >> 3, h = bh & 7;

  if (tid < 128) {
    lcnt[tid] = 0;
    const float* zp = Z + (b * 32 + h) * 1024 + (rt << 7) + tid;
    float z0 = zp[0], z1 = zp[8192], z2 = zp[16384], z3 = zp[24576];
    rzl[tid] = 1.0f / ((z0 * z1) * (z2 * z3));
    tzl[0][tid] = TTHR * z0;
  }
  {
    const int panel = b * 32 + h;
    stage_tile_s(Qs + (panel << 16) + (rt << 13), 64, Asm, tid);
    stage_tile_s(Ks + (panel << 16) + (ct << 13), 64, Bsm, tid);
  }
  __syncthreads();

  float prod[4][4][4];
#pragma unroll
  for (int mi = 0; mi < 4; ++mi)
#pragma unroll
    for (int ni = 0; ni < 4; ++ni)
#pragma unroll
      for (int r = 0; r < 4; ++r) prod[mi][ni][r] = 1.0f;

  const int kstA[3] = {0, 0, 4}, kstB[3] = {0, 4, 0};
#pragma unroll 1
  for (int l = 0; l < 4; ++l) {
    f32x4 acc[4][4] = {};
#pragma unroll
    for (int ks = 0; ks < 3; ++ks) {
      half8v af[4], bf[4];
#pragma unroll
      for (int mi = 0; mi < 4; ++mi) {
        const int row = (wr << 6) + (mi << 4) + lrow;
        const int xg = (kstA[ks] + lk) ^ (row & 7);
        af[mi] = *(const half8v*)&Asm[((row << 3) + xg) << 3];
      }
#pragma unroll
      for (int ni = 0; ni < 4; ++ni) {
        const int col = (wc << 6) + (ni << 4) + lrow;
        const int xg = (kstB[ks] + lk) ^ (col & 7);
        bf[ni] = *(const half8v*)&Bsm[((col << 3) + xg) << 3];
      }
#pragma unroll
      for (int mi = 0; mi < 4; ++mi)
#pragma unroll
        for (int ni = 0; ni < 4; ++ni)
          acc[mi][ni] = __builtin_amdgcn_mfma_f32_16x16x32_f16(af[mi], bf[ni], acc[mi][ni], 0, 0, 0);
    }
    __syncthreads();                    // LDS frag reads complete
    if (l < 3) {                        // overlap next stage with exp/prod
      const int panel = b * 32 + (l + 1) * 8 + h;
      stage_tile_s(Qs + (panel << 16) + (rt << 13), 64, Asm, tid);
      stage_tile_s(Ks + (panel << 16) + (ct << 13), 64, Bsm, tid);
      if (tid < 128) tzl[(l + 1) & 1][tid] = TTHR * Z[panel * 1024 + (rt << 7) + tid];
    }
#pragma unroll
    for (int mi = 0; mi < 4; ++mi)
#pragma unroll
      for (int reg = 0; reg < 4; ++reg) {
        const float tz = tzl[l & 1][(wr << 6) + (mi << 4) + (lk << 2) + reg];
#pragma unroll
        for (int ni = 0; ni < 4; ++ni) {
          const float e = __expf(acc[mi][ni][reg]) - tz;
          prod[mi][ni][reg] *= fmaxf(e, 0.0f);
        }
      }
    if (l < 3) __syncthreads();         // stages drained
  }

#pragma unroll
  for (int mi = 0; mi < 4; ++mi)
#pragma unroll
    for (int ni = 0; ni < 4; ++ni)
#pragma unroll
      for (int reg = 0; reg < 4; ++reg) {
        const int rloc = (wr << 6) + (mi << 4) + (lk << 2) + reg;
        const float v = prod[mi][ni][reg] * rzl[rloc];
        if (v > 0.0f) {
          const int slot = atomicAdd(&lcnt[rloc], 1);
          if (slot < CAP) {
            const int rowc = (bh << 10) + (rt << 7) + rloc;
            const int mglob = (ct << 7) + (wc << 6) + (ni << 4) + lrow;
            cidx[(rowc * 8 + ct) * CAP + slot] = (unsigned short)mglob;
            cval[(rowc * 8 + ct) * CAP + slot] = v * YSCALE;
          }
        }
      }
  __syncthreads();
  if (tid < 128) {
    const int rowc = (bh << 10) + (rt << 7) + tid;
    ccnt[rowc * 8 + ct] = min(lcnt[tid], CAP);
  }
}

// ---------------- K4: sparse PV gather -> split-fp16 ys ----------------
__global__ __launch_bounds__(64) void k_pv(
    const float* __restrict__ Vp, const int* __restrict__ ccnt,
    const unsigned short* __restrict__ cidx, const float* __restrict__ cval,
    _Float16* __restrict__ ysh, _Float16* __restrict__ ysl)
{
  const int rowc = blockIdx.x;
  const int bh = rowc >> 10, n = rowc & 1023;
  const int b = bh >> 3, h = bh & 7;
  const int l0 = threadIdx.x >> 5, d = threadIdx.x & 31;
  const float* vA = Vp + ((b * 32 + l0 * 8 + h) << 15) + d;
  const float* vB = vA + (16 << 15);
  float y0 = 0.f, y1 = 0.f;
  for (int mcj = 0; mcj < 8; ++mcj) {
    const int cnt = ccnt[rowc * 8 + mcj];
    const int off = (rowc * 8 + mcj) * CAP;
    for (int i = 0; i < cnt; ++i) {
      const int m = cidx[off + i];
      const float w = cval[off + i];
      y0 = fmaf(w, vA[m * 32], y0);
      y1 = fmaf(w, vB[m * 32], y1);
    }
  }
  const int idx = ((b << 10) + n) * 1024 + l0 * 256 + h * 32 + d;
  _Float16 h0 = (_Float16)y0;
  ysh[idx] = h0;
  ysl[idx] = (_Float16)(y0 - (float)h0);
  _Float16 h1 = (_Float16)y1;
  ysh[idx + 512] = h1;
  ysl[idx + 512] = (_Float16)(y1 - (float)h1);
}

extern "C" void kernel_launch(void* const* d_in, const int* in_sizes, int n_in,
                              void* d_out, int out_size, void* d_ws, size_t ws_size,
                              hipStream_t stream)
{
  const float* x  = (const float*)d_in[0];
  const float* Wc = (const float*)d_in[1];
  const float* bc = (const float*)d_in[2];
  const float* Wp = (const float*)d_in[3];
  const float* bp = (const float*)d_in[4];
  float* out = (float*)d_out;
  (void)in_sizes; (void)n_in; (void)out_size;

  if (ws_size < 98828288ull) return;
  char* wsb = (char*)d_ws;
  float*          Vp   = (float*)wsb;
  _Float16*       Qs   = (_Float16*)(wsb + 16777216);
  _Float16*       Ks   = (_Float16*)(wsb + 33554432);
  float*          Z    = (float*)(wsb + 50331648);
  _Float16*       xh   = (_Float16*)(wsb + 50855936);
  _Float16*       xl   = (_Float16*)(wsb + 59244544);
  int*            ccnt = (int*)(wsb + 67633152);
  unsigned short* cidx = (unsigned short*)(wsb + 68681728);
  float*          cval = (float*)(wsb + 77070336);
  _Float16*       Wch  = (_Float16*)(wsb + 93847552);
  _Float16*       Wcl  = (_Float16*)(wsb + 94240768);
  _Float16*       Wph  = (_Float16*)(wsb + 94633984);
  _Float16*       Wpl  = (_Float16*)(wsb + 96731136);

  k_split_rm<<<dim3(4096), dim3(256), 0, stream>>>(x, xh, xl, 1048576);
  k_split_tr<<<dim3(192), dim3(256), 0, stream>>>(Wc, Wch, Wcl, 256, 768);
  k_split_tr<<<dim3(1024), dim3(256), 0, stream>>>(Wp, Wph, Wpl, 1024, 1024);
  // qkv: M=16384 K=256 N=768; BN=64 -> nbn=12, grid 128*12=1536
  k_gemm_split<1><<<dim3(1536), dim3(256), 0, stream>>>(
      xh, xl, Wch, Wcl, bc, 256, 2, 12, nullptr, Qs, Ks, Vp);
  k_score_sum<<<dim3(1024), dim3(256), 0, stream>>>(Qs, Ks, Z);
  k_comb2<<<dim3(2048), dim3(256), 0, stream>>>(Qs, Ks, Z, ccnt, cidx, cval);
  k_pv<<<dim3(32768), dim3(64), 0, stream>>>(Vp, ccnt, cidx, cval, xh, xl);
  // proj: M=4096 K=1024 N=1024; BN=64 -> nbn=16, grid 32*16=512
  k_gemm_split<0><<<dim3(512), dim3(256), 0, stream>>>(
      xh, xl, Wph, Wpl, bp, 1024, 4, 16, out, nullptr, nullptr, nullptr);
}

// Round 6
// 225.212 us; speedup vs baseline: 1.1762x; 1.1762x over previous
//
#include <hip/hip_runtime.h>

#define TTHR 0.001f
#define QSCALE 0.17677669529663687f   // 1/sqrt(32)
#define CAP 16
#define YSCALE 8388608.0f             // 2^23
#define YINV   1.1920928955078125e-07f // 2^-23

typedef _Float16 half4v __attribute__((ext_vector_type(4)));
typedef _Float16 half8v __attribute__((ext_vector_type(8)));
typedef float f32x4 __attribute__((ext_vector_type(4)));

// XCD-aware block swizzle: contiguous logical range per XCD (grid % 8 == 0).
__device__ __forceinline__ int xcd_bid() {
  return (blockIdx.x & 7) * ((int)gridDim.x >> 3) + ((int)blockIdx.x >> 3);
}

// ---- stage a 128x64-half tile into LDS, XOR-swizzled (256 threads) ----
// LDS granule (row, x) holds source granule (row, x ^ (row&7)); 16B granules.
// global_load_lds writes linearly (wave-uniform base + lane*16) -> inverse perm on source.
__device__ __forceinline__ void stage_tile_s(const _Float16* __restrict__ gsrc,
                                             int rowstride, _Float16* lds, int tid)
{
  const int lane = tid & 63;
  const int w4 = (tid >> 6) << 2;
#pragma unroll
  for (int r = 0; r < 4; ++r) {
    const int p = (w4 + r) * 64 + lane;
    const int row = p >> 3, xg = p & 7;
    __builtin_amdgcn_global_load_lds(
        (const __attribute__((address_space(1))) void*)(gsrc + row * rowstride + ((xg ^ (row & 7)) << 3)),
        (__attribute__((address_space(3))) void*)(lds + (w4 + r) * 512),
        16, 0, 0);
  }
}

// ---- stage a 64x64-half tile (256 threads) ----
__device__ __forceinline__ void stage_tile64(const _Float16* __restrict__ gsrc,
                                             int rowstride, _Float16* lds, int tid)
{
  const int lane = tid & 63;
  const int w2 = (tid >> 6) << 1;
#pragma unroll
  for (int r = 0; r < 2; ++r) {
    const int p = (w2 + r) * 64 + lane;
    const int row = p >> 3, xg = p & 7;
    __builtin_amdgcn_global_load_lds(
        (const __attribute__((address_space(1))) void*)(gsrc + row * rowstride + ((xg ^ (row & 7)) << 3)),
        (__attribute__((address_space(3))) void*)(lds + (w2 + r) * 512),
        16, 0, 0);
  }
}

// ---- 512-thread variants (8 waves): 64x64 tile (1 granule/thread) ----
__device__ __forceinline__ void stage_q64_512(const _Float16* __restrict__ gsrc,
                                              _Float16* lds, int tid)
{
  const int lane = tid & 63, w = tid >> 6;
  const int p = (w << 6) + lane;
  const int row = p >> 3, xg = p & 7;
  __builtin_amdgcn_global_load_lds(
      (const __attribute__((address_space(1))) void*)(gsrc + row * 64 + ((xg ^ (row & 7)) << 3)),
      (__attribute__((address_space(3))) void*)(lds + (w << 9)),
      16, 0, 0);
}

// ---- 512-thread: 128x64 tile (2 granules/thread) ----
__device__ __forceinline__ void stage_k128_512(const _Float16* __restrict__ gsrc,
                                               _Float16* lds, int tid)
{
  const int lane = tid & 63, w = tid >> 6;
#pragma unroll
  for (int r = 0; r < 2; ++r) {
    const int p = ((w << 1) + r) * 64 + lane;
    const int row = p >> 3, xg = p & 7;
    __builtin_amdgcn_global_load_lds(
        (const __attribute__((address_space(1))) void*)(gsrc + row * 64 + ((xg ^ (row & 7)) << 3)),
        (__attribute__((address_space(3))) void*)(lds + ((w << 1) + r) * 512),
        16, 0, 0);
  }
}

// ---------------- conversion kernels ----------------
__global__ __launch_bounds__(256) void k_split_rm(
    const float* __restrict__ in, _Float16* __restrict__ oh,
    _Float16* __restrict__ ol, int n4)
{
  const int i = blockIdx.x * 256 + threadIdx.x;
  if (i >= n4) return;
  float4 v = ((const float4*)in)[i];
  half4v h = {(_Float16)v.x, (_Float16)v.y, (_Float16)v.z, (_Float16)v.w};
  half4v l = {(_Float16)(v.x - (float)h[0]), (_Float16)(v.y - (float)h[1]),
              (_Float16)(v.z - (float)h[2]), (_Float16)(v.w - (float)h[3])};
  ((half4v*)oh)[i] = h;
  ((half4v*)ol)[i] = l;
}

__global__ __launch_bounds__(256) void k_split_tr(
    const float* __restrict__ in, _Float16* __restrict__ oh,
    _Float16* __restrict__ ol, int K, int N)
{
  __shared__ float t[32][33];
  const int nb = N >> 5;
  const int n0 = (blockIdx.x % nb) << 5, k0 = (blockIdx.x / nb) << 5;
  const int r = threadIdx.x >> 3, c4 = (threadIdx.x & 7) << 2;
  float4 v = *(const float4*)&in[(k0 + r) * N + n0 + c4];
  t[r][c4] = v.x; t[r][c4 + 1] = v.y; t[r][c4 + 2] = v.z; t[r][c4 + 3] = v.w;
  __syncthreads();
  float a0 = t[c4][r], a1 = t[c4 + 1][r], a2 = t[c4 + 2][r], a3 = t[c4 + 3][r];
  half4v h = {(_Float16)a0, (_Float16)a1, (_Float16)a2, (_Float16)a3};
  half4v l = {(_Float16)(a0 - (float)h[0]), (_Float16)(a1 - (float)h[1]),
              (_Float16)(a2 - (float)h[2]), (_Float16)(a3 - (float)h[3])};
  *(half4v*)&oh[(n0 + r) * K + k0 + c4] = h;
  *(half4v*)&ol[(n0 + r) * K + k0 + c4] = l;
}

// ---------------- split-fp16 MFMA GEMM, 128x64 tile, 2-phase dbuf ----------
template<int EPI>
__global__ __launch_bounds__(256) void k_gemm_split(
    const _Float16* __restrict__ Ah, const _Float16* __restrict__ Al,
    const _Float16* __restrict__ Bh, const _Float16* __restrict__ Bl,
    const float* __restrict__ bias, int K, int kclog, int nbn,
    float* __restrict__ out, _Float16* __restrict__ Qs,
    _Float16* __restrict__ Ks, float* __restrict__ Vp)
{
  __shared__ __align__(16) _Float16 Asm[2][8192];
  __shared__ __align__(16) _Float16 Bsm[2][4096];
  const int tid = threadIdx.x, lane = tid & 63, w = tid >> 6;
  const int wr = w >> 1, wc = w & 1;
  const int lrow = lane & 15, lk = lane >> 4;
  const int bid = xcd_bid();
  const int mt = bid / nbn, ct = bid % nbn;
  const int m0 = mt << 7, c0 = ct << 6;

  const int nch = 3 << kclog;
  const int kcm = (1 << kclog) - 1;
  stage_tile_s(Ah + (size_t)m0 * K, K, Asm[0], tid);
  stage_tile64(Bh + (size_t)c0 * K, K, Bsm[0], tid);
  __syncthreads();

  f32x4 acc[4][2] = {};
#pragma unroll 1
  for (int ch = 0; ch < nch; ++ch) {
    const int cur = ch & 1;
    if (ch + 1 < nch) {
      const int ch2 = ch + 1;
      const int phase = ch2 >> kclog, kc = ch2 & kcm;
      const _Float16* As = (phase == 2) ? Al : Ah;
      const _Float16* Bs = (phase == 1) ? Bl : Bh;
      stage_tile_s(As + (size_t)m0 * K + (kc << 6), K, Asm[cur ^ 1], tid);
      stage_tile64(Bs + (size_t)c0 * K + (kc << 6), K, Bsm[cur ^ 1], tid);
    }
#pragma unroll
    for (int ks = 0; ks < 2; ++ks) {
      half8v af[4], bf[2];
#pragma unroll
      for (int mi = 0; mi < 4; ++mi) {
        const int row = (wr << 6) + (mi << 4) + lrow;
        const int xg = ((ks << 2) + lk) ^ (row & 7);
        af[mi] = *(const half8v*)&Asm[cur][((row << 3) + xg) << 3];
      }
#pragma unroll
      for (int ni = 0; ni < 2; ++ni) {
        const int col = (wc << 5) + (ni << 4) + lrow;
        const int xg = ((ks << 2) + lk) ^ (col & 7);
        bf[ni] = *(const half8v*)&Bsm[cur][((col << 3) + xg) << 3];
      }
#pragma unroll
      for (int mi = 0; mi < 4; ++mi)
#pragma unroll
        for (int ni = 0; ni < 2; ++ni)
          acc[mi][ni] = __builtin_amdgcn_mfma_f32_16x16x32_f16(af[mi], bf[ni], acc[mi][ni], 0, 0, 0);
    }
    __syncthreads();
  }

#pragma unroll
  for (int ni = 0; ni < 2; ++ni) {
    const int c = c0 + (wc << 5) + (ni << 4) + lrow;
    const float bv = bias[c];
    if (EPI == 0) {
#pragma unroll
      for (int mi = 0; mi < 4; ++mi)
#pragma unroll
        for (int reg = 0; reg < 4; ++reg) {
          const int m = m0 + (wr << 6) + (mi << 4) + (lk << 2) + reg;
          out[m * 1024 + c] = acc[mi][ni][reg] * YINV + bv;
        }
    } else {
      const int part = c >> 8, cc = c & 255;
      const int h = cc >> 5, d = cc & 31;
#pragma unroll
      for (int mi = 0; mi < 4; ++mi)
#pragma unroll
        for (int reg = 0; reg < 4; ++reg) {
          const int m = m0 + (wr << 6) + (mi << 4) + (lk << 2) + reg;
          const int b = m >> 12, n = (m >> 2) & 1023, l = m & 3;
          const int panel = b * 32 + l * 8 + h;
          float v = acc[mi][ni][reg] + bv;
          if (part == 2) {
            Vp[(panel << 15) + n * 32 + d] = v;
          } else {
            _Float16* dst = part ? Ks : Qs;
            if (!part) v *= QSCALE;
            _Float16 hv = (_Float16)v;
            _Float16 lv = (_Float16)(v - (float)hv);
            dst[(panel << 16) + n * 64 + d] = hv;
            dst[(panel << 16) + n * 64 + 32 + d] = lv;
          }
        }
    }
  }
}

// ---------------- K2: scores -> exp -> row sums Z (per-row blocks) ----------
__global__ __launch_bounds__(256) void k_score_sum(
    const _Float16* __restrict__ Qs, const _Float16* __restrict__ Ks,
    float* __restrict__ Z)
{
  __shared__ __align__(16) _Float16 Qsm[8192];
  __shared__ __align__(16) _Float16 Ksm[2][8192];
  __shared__ float Zsh[128];
  const int tid = threadIdx.x, lane = tid & 63, w = tid >> 6;
  const int wr = w >> 1, wc = w & 1;
  const int lrow = lane & 15, lk = lane >> 4;
  const int bid = xcd_bid();
  const int rt = bid & 7, panel = bid >> 3;

  stage_tile_s(Qs + (panel << 16) + (rt << 13), 64, Qsm, tid);
  stage_tile_s(Ks + (panel << 16), 64, Ksm[0], tid);
  if (tid < 128) Zsh[tid] = 0.0f;
  __syncthreads();

  const int kstA[3] = {0, 0, 4}, kstB[3] = {0, 4, 0};
  half8v af[3][4];
#pragma unroll
  for (int ks = 0; ks < 3; ++ks)
#pragma unroll
    for (int mi = 0; mi < 4; ++mi) {
      const int row = (wr << 6) + (mi << 4) + lrow;
      const int xg = (kstA[ks] + lk) ^ (row & 7);
      af[ks][mi] = *(const half8v*)&Qsm[((row << 3) + xg) << 3];
    }

  float rsum[4][4] = {};
#pragma unroll 1
  for (int ct = 0; ct < 8; ++ct) {
    const int cur = ct & 1;
    if (ct < 7)
      stage_tile_s(Ks + (panel << 16) + ((ct + 1) << 13), 64, Ksm[cur ^ 1], tid);
    f32x4 acc[4][4] = {};
#pragma unroll
    for (int ks = 0; ks < 3; ++ks) {
      half8v bf[4];
#pragma unroll
      for (int ni = 0; ni < 4; ++ni) {
        const int col = (wc << 6) + (ni << 4) + lrow;
        const int xg = (kstB[ks] + lk) ^ (col & 7);
        bf[ni] = *(const half8v*)&Ksm[cur][((col << 3) + xg) << 3];
      }
#pragma unroll
      for (int mi = 0; mi < 4; ++mi)
#pragma unroll
        for (int ni = 0; ni < 4; ++ni)
          acc[mi][ni] = __builtin_amdgcn_mfma_f32_16x16x32_f16(af[ks][mi], bf[ni], acc[mi][ni], 0, 0, 0);
    }
#pragma unroll
    for (int mi = 0; mi < 4; ++mi)
#pragma unroll
      for (int reg = 0; reg < 4; ++reg)
#pragma unroll
        for (int ni = 0; ni < 4; ++ni)
          rsum[mi][reg] += __expf(acc[mi][ni][reg]);
    __syncthreads();
  }

#pragma unroll
  for (int mi = 0; mi < 4; ++mi)
#pragma unroll
    for (int reg = 0; reg < 4; ++reg) {
      float s = rsum[mi][reg];
      s += __shfl_xor(s, 1, 64);
      s += __shfl_xor(s, 2, 64);
      s += __shfl_xor(s, 4, 64);
      s += __shfl_xor(s, 8, 64);
      if (lrow == 0) atomicAdd(&Zsh[(wr << 6) + (mi << 4) + (lk << 2) + reg], s);
    }
  __syncthreads();
  if (tid < 128) Z[panel * 1024 + (rt << 7) + tid] = Zsh[tid];
}

// ---------------- K3: scores x4 levels -> product -> sparse emit ------------
// 512 thr = 8 waves (2 row x 4 col); block tile 64 rows x 128 cols.
// Flat 32-iter loop over (ct, level), 2-phase LDS dbuf: stage(it+1); compute(it); barrier.
// prod_l relu(exp(s)/Z - T) == (prod_l max(exp(s) - T*Z_l, 0)) / prod_l Z_l
__global__ __launch_bounds__(512) void k_comb2(
    const _Float16* __restrict__ Qs, const _Float16* __restrict__ Ks,
    const float* __restrict__ Z, int* __restrict__ ccnt,
    unsigned short* __restrict__ cidx, float* __restrict__ cval)
{
  __shared__ __align__(16) _Float16 Sm[2][12288];   // [buf][Q 4096 halfs | K 8192 halfs]
  __shared__ float tzall[4][64];
  __shared__ float rz[64];
  __shared__ int lcnt[64];
  const int tid = threadIdx.x, lane = tid & 63, w = tid >> 6;
  const int wr = w >> 2, wc = w & 3;
  const int lrow = lane & 15, lk = lane >> 4;
  const int s = (blockIdx.x & 7) * 64 + ((int)blockIdx.x >> 3);  // XCD chunks of 64 = 4 bh
  const int bh = s >> 4, rt = s & 15;
  const int b = bh >> 3, h = bh & 7;
  const int pbase = b * 32 + h;                      // level stride = 8 panels

  // prologue: stage (ct=0, l=0) into buf 0
  stage_q64_512(Qs + (pbase << 16) + (rt << 12), Sm[0], tid);
  stage_k128_512(Ks + (pbase << 16), Sm[0] + 4096, tid);
  if (tid < 256) {
    const int l = tid >> 6, r = tid & 63;
    tzall[l][r] = TTHR * Z[(pbase + l * 8) * 1024 + (rt << 6) + r];
  }
  if (tid < 64) {
    const float* zp = Z + pbase * 1024 + (rt << 6) + tid;
    rz[tid] = 1.0f / ((zp[0] * zp[8192]) * (zp[16384] * zp[24576]));
  }
  __syncthreads();

  const int kstA[3] = {0, 0, 4}, kstB[3] = {0, 4, 0};
  float prod[2][2][4];

#pragma unroll 1
  for (int it = 0; it < 32; ++it) {
    const int l = it & 3, ct = it >> 2, cur = it & 1;
    if (it + 1 < 32) {                                // prefetch next (ct,l)
      const int l2 = (it + 1) & 3, ct2 = (it + 1) >> 2;
      _Float16* nb = Sm[cur ^ 1];
      stage_q64_512(Qs + ((pbase + l2 * 8) << 16) + (rt << 12), nb, tid);
      stage_k128_512(Ks + ((pbase + l2 * 8) << 16) + (ct2 << 13), nb + 4096, tid);
    }
    if (l == 0 && tid < 64) lcnt[tid] = 0;

    f32x4 acc[2][2] = {};
#pragma unroll
    for (int ks = 0; ks < 3; ++ks) {
      half8v af[2], bf[2];
#pragma unroll
      for (int mi = 0; mi < 2; ++mi) {
        const int row = (wr << 5) + (mi << 4) + lrow;
        const int xg = (kstA[ks] + lk) ^ (row & 7);
        af[mi] = *(const half8v*)&Sm[cur][((row << 3) + xg) << 3];
      }
#pragma unroll
      for (int ni = 0; ni < 2; ++ni) {
        const int col = (wc << 5) + (ni << 4) + lrow;
        const int xg = (kstB[ks] + lk) ^ (col & 7);
        bf[ni] = *(const half8v*)&Sm[cur][4096 + (((col << 3) + xg) << 3)];
      }
#pragma unroll
      for (int mi = 0; mi < 2; ++mi)
#pragma unroll
        for (int ni = 0; ni < 2; ++ni)
          acc[mi][ni] = __builtin_amdgcn_mfma_f32_16x16x32_f16(af[mi], bf[ni], acc[mi][ni], 0, 0, 0);
    }

#pragma unroll
    for (int mi = 0; mi < 2; ++mi)
#pragma unroll
      for (int reg = 0; reg < 4; ++reg) {
        const float tz = tzall[l][(wr << 5) + (mi << 4) + (lk << 2) + reg];
#pragma unroll
        for (int ni = 0; ni < 2; ++ni) {
          const float e = fmaxf(__expf(acc[mi][ni][reg]) - tz, 0.0f);
          prod[mi][ni][reg] = (l == 0) ? e : prod[mi][ni][reg] * e;
        }
      }

    if (l == 3) {
#pragma unroll
      for (int mi = 0; mi < 2; ++mi)
#pragma unroll
        for (int ni = 0; ni < 2; ++ni)
#pragma unroll
          for (int reg = 0; reg < 4; ++reg) {
            const int rloc = (wr << 5) + (mi << 4) + (lk << 2) + reg;
            const float v = prod[mi][ni][reg] * rz[rloc];
            if (v > 0.0f) {
              const int slot = atomicAdd(&lcnt[rloc], 1);
              if (slot < CAP) {
                const int rowc = (bh << 10) + (rt << 6) + rloc;
                const int mglob = (ct << 7) + (wc << 5) + (ni << 4) + lrow;
                cidx[(rowc * 8 + ct) * CAP + slot] = (unsigned short)mglob;
                cval[(rowc * 8 + ct) * CAP + slot] = v * YSCALE;
              }
            }
          }
      __syncthreads();
      if (tid < 64)
        ccnt[((bh << 10) + (rt << 6) + tid) * 8 + ct] = min(lcnt[tid], CAP);
    }
    __syncthreads();
  }
}

// ---------------- K4: sparse PV gather -> split-fp16 ys ----------------
__global__ __launch_bounds__(512) void k_pv(
    const float* __restrict__ Vp, const int* __restrict__ ccnt,
    const unsigned short* __restrict__ cidx, const float* __restrict__ cval,
    _Float16* __restrict__ ysh, _Float16* __restrict__ ysl)
{
  const int rowc = blockIdx.x * 8 + (threadIdx.x >> 6);
  const int lane = threadIdx.x & 63;
  const int bh = rowc >> 10, n = rowc & 1023;
  const int b = bh >> 3, h = bh & 7;
  const int l0 = lane >> 5, d = lane & 31;
  const float* vA = Vp + ((b * 32 + l0 * 8 + h) << 15) + d;
  const float* vB = vA + (16 << 15);
  float y0 = 0.f, y1 = 0.f;
  for (int mcj = 0; mcj < 8; ++mcj) {
    const int cnt = ccnt[rowc * 8 + mcj];
    const int off = (rowc * 8 + mcj) * CAP;
    for (int i = 0; i < cnt; ++i) {
      const int m = cidx[off + i];
      const float w = cval[off + i];
      y0 = fmaf(w, vA[m * 32], y0);
      y1 = fmaf(w, vB[m * 32], y1);
    }
  }
  const int idx = ((b << 10) + n) * 1024 + l0 * 256 + h * 32 + d;
  _Float16 h0 = (_Float16)y0;
  ysh[idx] = h0;
  ysl[idx] = (_Float16)(y0 - (float)h0);
  _Float16 h1 = (_Float16)y1;
  ysh[idx + 512] = h1;
  ysl[idx + 512] = (_Float16)(y1 - (float)h1);
}

extern "C" void kernel_launch(void* const* d_in, const int* in_sizes, int n_in,
                              void* d_out, int out_size, void* d_ws, size_t ws_size,
                              hipStream_t stream)
{
  const float* x  = (const float*)d_in[0];
  const float* Wc = (const float*)d_in[1];
  const float* bc = (const float*)d_in[2];
  const float* Wp = (const float*)d_in[3];
  const float* bp = (const float*)d_in[4];
  float* out = (float*)d_out;
  (void)in_sizes; (void)n_in; (void)out_size;

  if (ws_size < 98828288ull) return;
  char* wsb = (char*)d_ws;
  float*          Vp   = (float*)wsb;
  _Float16*       Qs   = (_Float16*)(wsb + 16777216);
  _Float16*       Ks   = (_Float16*)(wsb + 33554432);
  float*          Z    = (float*)(wsb + 50331648);
  _Float16*       xh   = (_Float16*)(wsb + 50855936);
  _Float16*       xl   = (_Float16*)(wsb + 59244544);
  int*            ccnt = (int*)(wsb + 67633152);
  unsigned short* cidx = (unsigned short*)(wsb + 68681728);
  float*          cval = (float*)(wsb + 77070336);
  _Float16*       Wch  = (_Float16*)(wsb + 93847552);
  _Float16*       Wcl  = (_Float16*)(wsb + 94240768);
  _Float16*       Wph  = (_Float16*)(wsb + 94633984);
  _Float16*       Wpl  = (_Float16*)(wsb + 96731136);

  k_split_rm<<<dim3(4096), dim3(256), 0, stream>>>(x, xh, xl, 1048576);
  k_split_tr<<<dim3(192), dim3(256), 0, stream>>>(Wc, Wch, Wcl, 256, 768);
  k_split_tr<<<dim3(1024), dim3(256), 0, stream>>>(Wp, Wph, Wpl, 1024, 1024);
  // qkv: M=16384 K=256 N=768; BN=64 -> nbn=12, grid 128*12=1536
  k_gemm_split<1><<<dim3(1536), dim3(256), 0, stream>>>(
      xh, xl, Wch, Wcl, bc, 256, 2, 12, nullptr, Qs, Ks, Vp);
  k_score_sum<<<dim3(1024), dim3(256), 0, stream>>>(Qs, Ks, Z);
  k_comb2<<<dim3(512), dim3(512), 0, stream>>>(Qs, Ks, Z, ccnt, cidx, cval);
  k_pv<<<dim3(4096), dim3(512), 0, stream>>>(Vp, ccnt, cidx, cval, xh, xl);
  // proj: M=4096 K=1024 N=1024; BN=64 -> nbn=16, grid 32*16=512
  k_gemm_split<0><<<dim3(512), dim3(256), 0, stream>>>(
      xh, xl, Wph, Wpl, bp, 1024, 4, 16, out, nullptr, nullptr, nullptr);
}